// Round 2
// baseline (1051.670 us; speedup 1.0000x reference)
//
#include <hip/hip_runtime.h>
#include <cstdint>
#include <cstddef>

typedef __bf16 bf16;
typedef __bf16 bf16x2 __attribute__((ext_vector_type(2)));
typedef __bf16 bf16x8 __attribute__((ext_vector_type(8)));
typedef float  f32x4  __attribute__((ext_vector_type(4)));

#define DEV __device__ __forceinline__

constexpr int Bc = 2, Sc = 2048, Dc = 2048, Hc = 16, KVc = 4, HDc = 128, FFNc = 5632;
constexpr int Rc = Bc * Sc;  // 4096 rows

DEV void async16(const bf16* g, bf16* l) {
  __builtin_amdgcn_global_load_lds((const __attribute__((address_space(1))) void*)g,
                                   (__attribute__((address_space(3))) void*)l, 16, 0, 0);
}

// ---------------- weight transpose + fp32->bf16 cast: out[n][k] = in[k][n] ----
__global__ void transpose_cast(const float* __restrict__ in, bf16* __restrict__ out,
                               int K, int N, int rowoff, int ldout) {
  __shared__ float tile[32][33];
  int k0 = blockIdx.y * 32, n0 = blockIdx.x * 32;
  int tx = threadIdx.x, ty = threadIdx.y;
  for (int r = ty; r < 32; r += 8)
    tile[r][tx] = in[(size_t)(k0 + r) * N + n0 + tx];
  __syncthreads();
  for (int r = ty; r < 32; r += 8)
    out[(size_t)(rowoff + n0 + r) * ldout + k0 + tx] = (bf16)tile[tx][r];
}

// ---------------- V transpose: vht[b][g][d][s] = qkvb[b*S+s][2560+g*128+d] ---
__global__ void transpose_v(const bf16* __restrict__ qkvb, bf16* __restrict__ vht) {
  __shared__ bf16 tile[32][33];
  int s0 = blockIdx.x * 32, d0 = blockIdx.y * 32, bg = blockIdx.z;  // bg = b*4+g
  int tx = threadIdx.x, ty = threadIdx.y;
  int b = bg >> 2, g = bg & 3;
  const bf16* src = qkvb + (size_t)(b * Sc) * 3072 + 2560 + g * 128;
  for (int r = ty; r < 32; r += 8)
    tile[r][tx] = src[(size_t)(s0 + r) * 3072 + d0 + tx];
  __syncthreads();
  bf16* dst = vht + ((size_t)bg * HDc) * Sc;
  for (int r = ty; r < 32; r += 8)
    dst[(size_t)(d0 + r) * Sc + s0 + tx] = tile[tx][r];
}

// ---------------- row RMSNorm (D=2048) + cast to bf16 ------------------------
__global__ void rmsnorm_cast(const float* __restrict__ x, const float* __restrict__ w,
                             bf16* __restrict__ out) {
  __shared__ float red[4];
  int row = blockIdx.x, tid = threadIdx.x;
  const float* xr = x + (size_t)row * Dc;
  float ss = 0.f;
#pragma unroll
  for (int i = 0; i < Dc / 256; ++i) { float v = xr[tid + i * 256]; ss += v * v; }
  for (int off = 32; off; off >>= 1) ss += __shfl_xor(ss, off);
  if ((tid & 63) == 0) red[tid >> 6] = ss;
  __syncthreads();
  float rstd = rsqrtf((red[0] + red[1] + red[2] + red[3]) * (1.f / Dc) + 1e-6f);
  bf16* orow = out + (size_t)row * Dc;
#pragma unroll
  for (int i = 0; i < Dc / 256; ++i) {
    int j = tid + i * 256;
    orow[j] = (bf16)(xr[j] * rstd * w[j]);
  }
}

// swizzled bf16-element offset inside a [rows][32] staged tile (128B physical rows,
// granule-XOR by physical-row&7; matches the pre-swizzled global source in stage()).
DEV int swzofs(int r, int quad) {
  int pr = r >> 1;
  int g = (((r & 1) << 2) | quad) ^ (pr & 7);
  return pr * 64 + g * 8;
}

// ---------------- 256-wide phase-split GEMM (T2+T3+T4+T5) --------------------
// C[M,N] = A[M,K] * Bt[N,K]^T ; K % 32 == 0, M % 256 == 0, N % BN == 0.
// 8 waves (2m x 4n), per-wave 128 x (NF*16) output. BK=32, ring-3 LDS buffers,
// counted vmcnt (never 0 mid-loop), conflict-free swizzled ds_read_b128.
// MODE 1: v=clip(beta*velin+c); velout=v; Cf = xin + v
// MODE 2: store bf16 C at ldc
// MODE 3: Cf = xin + c (in-place residual ok)
template <int MODE, int NF>  // NF: B n-frags per wave. 4 -> BN=256, 2 -> BN=128
__global__ __launch_bounds__(512, 2) void gemm256(
    const bf16* __restrict__ A, int lda, const bf16* __restrict__ Bt,
    float* __restrict__ Cf, bf16* __restrict__ Cb,
    const float* __restrict__ xin, const float* __restrict__ velin,
    const float* __restrict__ lbp, float* __restrict__ velout,
    int K, int ldc, int nbx) {
  constexpr int BN = NF * 64;
  constexpr int BLD = 2 + BN / 128;  // per-thread stage loads per K-tile (A:2 + B:1|2)
  __shared__ bf16 Asb[3][256 * 32];  // 16KB per ring
  __shared__ bf16 Bsb[3][BN * 32];   // 8/16KB per ring
  const int tid = threadIdx.x, lane = tid & 63, w = tid >> 6;
  const int quad = lane >> 4, l15 = lane & 15;
  const int wm = w >> 2, wn = w & 3;

  // bijective XCD-chunked swizzle (m204): consecutive swz share an XCD + A-panel
  const int nwg = gridDim.x, bid = blockIdx.x;
  const int qq = nwg >> 3, rr = nwg & 7, xcd = bid & 7, lid = bid >> 3;
  const int swz = (xcd < rr ? xcd * (qq + 1) : rr * (qq + 1) + (xcd - rr) * qq) + lid;
  const int m0 = (swz / nbx) * 256, n0 = (swz % nbx) * BN;

  const int NT = K >> 5;

  f32x4 acc[8][NF];
  const f32x4 zf = {0.f, 0.f, 0.f, 0.f};
#pragma unroll
  for (int i = 0; i < 8; ++i)
#pragma unroll
    for (int j = 0; j < NF; ++j) acc[i][j] = zf;

  // stage one K-tile (256x32 of A, BNx32 of B) into ring buffer `ring`.
  // LDS dest is linear (wave-uniform base + lane*16); global source is
  // pre-swizzled with the same involution swzofs() reads with.
  auto stage = [&](int kt, int ring) {
    const int k0 = kt * 32;
#pragma unroll
    for (int i = 0; i < 2; ++i) {            // A: 16 wave-loads, 2 per wave
      int fi = w * 2 + i;
      int pr = fi * 8 + (lane >> 3), g0 = (lane & 7) ^ (pr & 7);
      int r = pr * 2 + (g0 >> 2), c8 = (g0 & 3) * 8;
      async16(A + (size_t)(m0 + r) * lda + k0 + c8, Asb[ring] + fi * 512);
    }
#pragma unroll
    for (int i = 0; i < BN / 128; ++i) {     // B: BN/16 wave-loads
      int fi = w * (BN / 128) + i;
      int pr = fi * 8 + (lane >> 3), g0 = (lane & 7) ^ (pr & 7);
      int r = pr * 2 + (g0 >> 2), c8 = (g0 & 3) * 8;
      async16(Bt + (size_t)(n0 + r) * K + k0 + c8, Bsb[ring] + fi * 512);
    }
  };

  // prologue: tiles 0 and 1 in flight; drain tile 0, keep tile 1 flying
  stage(0, 0);
  stage(1, 1);
  if constexpr (BLD == 4) asm volatile("s_waitcnt vmcnt(4)" ::: "memory");
  else                    asm volatile("s_waitcnt vmcnt(3)" ::: "memory");
  __builtin_amdgcn_s_barrier();

  int r0 = 0;
  for (int kt = 0; kt < NT; ++kt) {
    int r2 = r0 + 2; if (r2 >= 3) r2 -= 3;
    const bf16* Ak = Asb[r0];
    const bf16* Bk = Bsb[r0];
    if (kt + 2 < NT) stage(kt + 2, r2);  // issue-early: 2 tiles of lookahead

    // ---- phase 0: B frags + A rows 0..63, one C-half ----
    bf16x8 bfr[NF], af[4];
#pragma unroll
    for (int j = 0; j < NF; ++j)
      bfr[j] = *(const bf16x8*)(Bk + swzofs(wn * (NF * 16) + j * 16 + l15, quad));
#pragma unroll
    for (int i = 0; i < 4; ++i)
      af[i] = *(const bf16x8*)(Ak + swzofs(wm * 128 + i * 16 + l15, quad));
    __builtin_amdgcn_s_barrier();
    __builtin_amdgcn_s_setprio(1);
#pragma unroll
    for (int i = 0; i < 4; ++i)
#pragma unroll
      for (int j = 0; j < NF; ++j)
        acc[i][j] = __builtin_amdgcn_mfma_f32_16x16x32_bf16(af[i], bfr[j], acc[i][j], 0, 0, 0);
    __builtin_amdgcn_s_setprio(0);
    __builtin_amdgcn_s_barrier();

    // ---- phase 1: A rows 64..127, other C-half ----
#pragma unroll
    for (int i = 0; i < 4; ++i)
      af[i] = *(const bf16x8*)(Ak + swzofs(wm * 128 + 64 + i * 16 + l15, quad));
    __builtin_amdgcn_s_barrier();
    __builtin_amdgcn_s_setprio(1);
#pragma unroll
    for (int i = 0; i < 4; ++i)
#pragma unroll
      for (int j = 0; j < NF; ++j)
        acc[4 + i][j] = __builtin_amdgcn_mfma_f32_16x16x32_bf16(af[i], bfr[j], acc[4 + i][j], 0, 0, 0);
    __builtin_amdgcn_s_setprio(0);

    // ---- tile end: counted wait (drains tile kt+1; tile kt+2 stays in flight) ----
    if (kt + 2 < NT) {
      if constexpr (BLD == 4) asm volatile("s_waitcnt vmcnt(4)" ::: "memory");
      else                    asm volatile("s_waitcnt vmcnt(3)" ::: "memory");
    } else if (kt + 2 == NT) {
      asm volatile("s_waitcnt vmcnt(0)" ::: "memory");  // epilogue drain
    }
    __builtin_amdgcn_sched_barrier(0);
    __builtin_amdgcn_s_barrier();
    r0 = (r0 == 2) ? 0 : r0 + 1;
  }

  float beta = 0.f;
  if (MODE == 1) beta = 1.f / (1.f + __expf(-lbp[0]));
#pragma unroll
  for (int i = 0; i < 8; ++i) {
#pragma unroll
    for (int j = 0; j < NF; ++j) {
#pragma unroll
      for (int r = 0; r < 4; ++r) {
        int row = m0 + wm * 128 + i * 16 + quad * 4 + r;
        int col = n0 + wn * (NF * 16) + j * 16 + l15;
        size_t idx = (size_t)row * ldc + col;
        float c = acc[i][j][r];
        if (MODE == 1) {
          float v = beta * velin[idx] + c;
          v = fminf(8.f, fmaxf(-8.f, v));
          velout[idx] = v;
          Cf[idx] = xin[idx] + v;
        } else if (MODE == 2) {
          Cb[idx] = (bf16)c;
        } else {
          Cf[idx] = xin[idx] + c;
        }
      }
    }
  }
}

// ---------------- per-head RMSNorm + RoPE for q,k (v handled separately) -----
// q outputs pre-scaled by 1/sqrt(HD).
__global__ __launch_bounds__(256) void qk_norm_rope(
    const bf16* __restrict__ qkv, const float* __restrict__ qw, const float* __restrict__ kw,
    const float* __restrict__ freqs, bf16* __restrict__ qh, bf16* __restrict__ kh) {
  int row = blockIdx.x;  // b*S + s
  int b = row >> 11, s = row & 2047;
  int tid = threadIdx.x, wvid = tid >> 6, lane = tid & 63;
  float cs = freqs[(size_t)(s * 64 + lane) * 2 + 0];
  float sn = freqs[(size_t)(s * 64 + lane) * 2 + 1];
  for (int slot = wvid; slot < 20; slot += 4) {
    const bf16* base = qkv + (size_t)row * 3072 + slot * 128;
    float t0 = (float)base[2 * lane], t1 = (float)base[2 * lane + 1];
    float ss = t0 * t0 + t1 * t1;
    for (int off = 32; off; off >>= 1) ss += __shfl_xor(ss, off);
    float rstd = rsqrtf(ss * (1.f / 128.f) + 1e-6f);
    const float* w = (slot < 16) ? qw : kw;
    float sc = (slot < 16) ? 0.08838834764831845f : 1.f;  // fold 1/sqrt(128) into q
    float n0 = t0 * rstd * w[2 * lane], n1 = t1 * rstd * w[2 * lane + 1];
    bf16x2 o;
    o[0] = (bf16)((n0 * cs - n1 * sn) * sc);
    o[1] = (bf16)((n0 * sn + n1 * cs) * sc);
    if (slot < 16)
      *(bf16x2*)(qh + ((size_t)(b * Hc + slot) * Sc + s) * HDc + 2 * lane) = o;
    else
      *(bf16x2*)(kh + ((size_t)(b * KVc + (slot - 16)) * Sc + s) * HDc + 2 * lane) = o;
  }
}

// ---------------- strict-causal GQA flash attention (v2) ---------------------
// grid (16 pairs, H, B); block 256 = 4 waves; wave owns 16 q-rows.
// KVBLK=64, double-buffered async16 K/V staging (1 barrier/tile),
// XOR-swizzled LDS (conflict-free ds_read_b128), MFMA row-sum (P*ones),
// per-wave P scratch with no barrier, masking only on the diagonal tile.
__global__ __launch_bounds__(256) void flash_attn(
    const bf16* __restrict__ qh, const bf16* __restrict__ kh, const bf16* __restrict__ vht,
    bf16* __restrict__ attn) {
  __shared__ bf16 Ks[2][64 * 128];   // [k][d] linear, content XOR-swizzled by (row&15)<<4
  __shared__ bf16 Vs[2][128 * 64];   // [d][k] linear, content XOR-swizzled by (row&7)<<4
  __shared__ bf16 Ps[4][16 * 68];    // per-wave P transpose scratch, pitch 68 (2-way free)
  const int tid = threadIdx.x, lane = tid & 63, wvid = tid >> 6;
  const int quad = lane >> 4, l15 = lane & 15;
  const int pairp = blockIdx.x;
  const int h = blockIdx.y, b = blockIdx.z, g = h >> 2;
  const bf16* qbase = qh + (size_t)(b * Hc + h) * Sc * HDc;
  const bf16* kbase = kh + (size_t)(b * KVc + g) * Sc * HDc;
  const bf16* vbase = vht + (size_t)(b * KVc + g) * HDc * Sc;  // [d][s]
  const f32x4 zf = {0.f, 0.f, 0.f, 0.f};
  bf16* pw = Ps[wvid];

  bf16x8 ones;
#pragma unroll
  for (int e = 0; e < 8; ++e) ones[e] = (bf16)1.0f;

  // per-lane swizzled column offsets (bf16 units) for LDS fragment reads
  int kcol[4], vcol[2];
#pragma unroll
  for (int f = 0; f < 4; ++f) kcol[f] = ((f * 64 + quad * 16) ^ (l15 << 4)) >> 1;
#pragma unroll
  for (int ks = 0; ks < 2; ++ks) vcol[ks] = ((ks * 64 + quad * 16) ^ ((l15 & 7) << 4)) >> 1;

  // stage 64-k tile kt2 into buffer bsel: K rows + V^T rows, pre-swizzled source
  auto stage = [&](int kt2, int bsel) {
    const int k0s = kt2 * 64;
#pragma unroll
    for (int r = 0; r < 4; ++r) {
      int krow = (wvid * 4 + r) * 4 + quad;  // 0..63, wave-partitioned
      const bf16* src = kbase + (size_t)(k0s + krow) * HDc + ((l15 ^ (krow & 15)) * 8);
      async16(src, &Ks[bsel][(wvid * 4 + r) * 512]);
    }
#pragma unroll
    for (int r = 0; r < 4; ++r) {
      int vrow = (wvid * 4 + r) * 8 + (lane >> 3);  // 0..127
      int c8 = lane & 7;
      const bf16* src = vbase + (size_t)vrow * Sc + k0s + ((c8 ^ (vrow & 7)) * 8);
      async16(src, &Vs[bsel][(wvid * 4 + r) * 512]);
    }
  };

  for (int pass = 0; pass < 2; ++pass) {
    const int qt = pass ? 31 - pairp : pairp;
    const int q0 = qt * 64 + wvid * 16;

    bf16x8 qf[4];
#pragma unroll
    for (int f = 0; f < 4; ++f)
      qf[f] = *(const bf16x8*)(qbase + (size_t)(q0 + l15) * HDc + f * 32 + quad * 8);

    f32x4 Oa[8];
#pragma unroll
    for (int i = 0; i < 8; ++i) Oa[i] = zf;
    float m_i[4], l_i[4];
#pragma unroll
    for (int r = 0; r < 4; ++r) { m_i[r] = -3e38f; l_i[r] = 0.f; }

    const int ntiles = qt + 1;  // uniform across waves; only tile qt is masked

    __syncthreads();            // previous pass's readers of buf0 are done
    stage(0, 0);

    for (int kt = 0; kt < ntiles; ++kt) {
      const int buf = kt & 1;
      const int k0 = kt * 64;
      __syncthreads();          // staged tile kt landed; prior readers of buf^1 done
      if (kt + 1 < ntiles) stage(kt + 1, buf ^ 1);

      // ---- QK^T over 4 k-subtiles of 16 ----
      f32x4 sc[4];
#pragma unroll
      for (int ks = 0; ks < 4; ++ks) {
        sc[ks] = zf;
#pragma unroll
        for (int f = 0; f < 4; ++f) {
          bf16x8 kf = *(const bf16x8*)(&Ks[buf][ks * 2048 + l15 * 128 + kcol[f]]);
          sc[ks] = __builtin_amdgcn_mfma_f32_16x16x32_bf16(qf[f], kf, sc[ks], 0, 0, 0);
        }
      }

      // ---- causal mask: only the diagonal tile ----
      if (kt == qt) {
#pragma unroll
        for (int r = 0; r < 4; ++r) {
          int qg = q0 + quad * 4 + r;
#pragma unroll
          for (int ks = 0; ks < 4; ++ks)
            if (k0 + ks * 16 + l15 >= qg) sc[ks][r] = -3e38f;  // strict causal k<q
        }
      }

      // ---- online softmax (max via shuffles; sum via MFMA below) ----
      float mx[4], al[4];
#pragma unroll
      for (int r = 0; r < 4; ++r)
        mx[r] = fmaxf(fmaxf(sc[0][r], sc[1][r]), fmaxf(sc[2][r], sc[3][r]));
#pragma unroll
      for (int off = 8; off; off >>= 1)
#pragma unroll
        for (int r = 0; r < 4; ++r) mx[r] = fmaxf(mx[r], __shfl_xor(mx[r], off));
#pragma unroll
      for (int r = 0; r < 4; ++r) {
        float mn = fmaxf(m_i[r], mx[r]);
        al[r] = __expf(m_i[r] - mn);
        m_i[r] = mn;
#pragma unroll
        for (int ks = 0; ks < 4; ++ks) {
          float p = (sc[ks][r] > -1e37f) ? __expf(sc[ks][r] - mn) : 0.f;
          sc[ks][r] = p;
        }
      }

      // ---- P -> per-wave LDS (wave-internal; compiler orders write->read) ----
#pragma unroll
      for (int r = 0; r < 4; ++r)
#pragma unroll
        for (int ks = 0; ks < 4; ++ks)
          pw[(quad * 4 + r) * 68 + ks * 16 + l15] = (bf16)sc[ks][r];

      // rescale O while the P writes land
#pragma unroll
      for (int i = 0; i < 8; ++i)
#pragma unroll
        for (int r = 0; r < 4; ++r) Oa[i][r] *= al[r];

      bf16x8 pf0 = *(const bf16x8*)(pw + l15 * 68 + quad * 8);
      bf16x8 pf1 = *(const bf16x8*)(pw + l15 * 68 + 32 + quad * 8);

      // row-sum l = P . 1 via 2 MFMAs (replaces 16 shuffle+adds)
      f32x4 ls = zf;
      ls = __builtin_amdgcn_mfma_f32_16x16x32_bf16(pf0, ones, ls, 0, 0, 0);
      ls = __builtin_amdgcn_mfma_f32_16x16x32_bf16(pf1, ones, ls, 0, 0, 0);

      // ---- PV over d=128 ----
#pragma unroll
      for (int i = 0; i < 8; ++i) {
        bf16x8 vf0 = *(const bf16x8*)(&Vs[buf][(i * 16 + l15) * 64 + vcol[0]]);
        Oa[i] = __builtin_amdgcn_mfma_f32_16x16x32_bf16(pf0, vf0, Oa[i], 0, 0, 0);
        bf16x8 vf1 = *(const bf16x8*)(&Vs[buf][(i * 16 + l15) * 64 + vcol[1]]);
        Oa[i] = __builtin_amdgcn_mfma_f32_16x16x32_bf16(pf1, vf1, Oa[i], 0, 0, 0);
      }
#pragma unroll
      for (int r = 0; r < 4; ++r) l_i[r] = l_i[r] * al[r] + ls[r];
    }

#pragma unroll
    for (int r = 0; r < 4; ++r) {
      float inv = (l_i[r] > 0.f) ? 1.f / l_i[r] : 0.f;  // q=0 row fully masked -> 0
      int qg = q0 + quad * 4 + r;
      bf16* orow = attn + (size_t)(b * Sc + qg) * Dc + h * HDc;
#pragma unroll
      for (int i = 0; i < 8; ++i) orow[i * 16 + l15] = (bf16)(Oa[i][r] * inv);
    }
  }
}

// ---------------- SwiGLU in-place: g[:, :5632] = silu(g1)*g3 -----------------
__global__ __launch_bounds__(256) void silu_mul_ip(bf16* __restrict__ g) {
  int row = blockIdx.y * 4 + (threadIdx.x >> 6);
  int j0 = (blockIdx.x * 64 + (threadIdx.x & 63)) * 8;
  bf16* p = g + (size_t)row * (2 * FFNc) + j0;
  const bf16x8 a = *(const bf16x8*)p;
  const bf16x8 bb = *(const bf16x8*)(p + FFNc);
  bf16x8 o;
#pragma unroll
  for (int e = 0; e < 8; ++e) {
    float xa = (float)a[e], xb = (float)bb[e];
    float s = xa / (1.f + __expf(-xa));
    o[e] = (bf16)(s * xb);
  }
  *(bf16x8*)p = o;
}

// ---------------- launch ------------------------------------------------------
extern "C" void kernel_launch(void* const* d_in, const int* in_sizes, int n_in,
                              void* d_out, int out_size, void* d_ws, size_t ws_size,
                              hipStream_t stream) {
  (void)in_sizes; (void)n_in; (void)out_size; (void)ws_size;
  const float* x    = (const float*)d_in[0];
  const float* vel  = (const float*)d_in[1];
  const float* frq  = (const float*)d_in[2];
  const float* prew = (const float*)d_in[3];
  const float* wq   = (const float*)d_in[4];
  const float* wk   = (const float*)d_in[5];
  const float* wvw  = (const float*)d_in[6];
  const float* wo   = (const float*)d_in[7];
  const float* qnw  = (const float*)d_in[8];
  const float* knw  = (const float*)d_in[9];
  const float* lb   = (const float*)d_in[10];
  const float* ffnw = (const float*)d_in[11];
  const float* w1   = (const float*)d_in[12];
  const float* w3   = (const float*)d_in[13];
  const float* w2   = (const float*)d_in[14];

  float* out0 = (float*)d_out;                  // final x (also residual scratch)
  float* out1 = out0 + (size_t)Rc * Dc;         // velocity

  // ---- workspace arena: ~132 MiB total ----
  char* ws = (char*)d_ws;
  bf16* W  = (bf16*)ws;                                   // 23.07 MB weight region (serial reuse)
  bf16* R1 = (bf16*)(ws + (size_t)23068672);              // 16.78 MB: hbuf -> attn -> normed
  bf16* G  = (bf16*)(ws + (size_t)23068672 + 16777216);   // 92.27 MB: qkv/heads -> gbuf
  bf16* hbuf   = R1;
  bf16* attn   = R1;
  bf16* normed = R1;
  bf16* qkvb   = G;                                       // 4096 x 3072 bf16
  bf16* qhb    = G + (size_t)4096 * 3072;                 // 2*16*2048*128
  bf16* khb    = qhb + (size_t)2 * 16 * 2048 * 128;       // 2*4*2048*128
  bf16* vht    = khb + (size_t)2 * 4 * 2048 * 128;        // V^T [b][g][128][2048]
  bf16* gbuf   = G;                                       // 4096 x 11264 (born after heads die)

  dim3 tb(32, 8);

  // QKV projection (M=4096, N=3072, K=2048) -> BN=256, 12x16 = 192 blocks
  transpose_cast<<<dim3(64, 64), tb, 0, stream>>>(wq, W, 2048, 2048, 0, 2048);
  transpose_cast<<<dim3(16, 64), tb, 0, stream>>>(wk, W, 2048, 512, 2048, 2048);
  transpose_cast<<<dim3(16, 64), tb, 0, stream>>>(wvw, W, 2048, 512, 2560, 2048);
  rmsnorm_cast<<<Rc, 256, 0, stream>>>(x, prew, hbuf);
  gemm256<2, 4><<<192, 512, 0, stream>>>(hbuf, 2048, W, nullptr, qkvb, nullptr, nullptr,
                                         nullptr, nullptr, 2048, 3072, 12);
  qk_norm_rope<<<Rc, 256, 0, stream>>>(qkvb, qnw, knw, frq, qhb, khb);
  transpose_v<<<dim3(64, 4, 8), tb, 0, stream>>>(qkvb, vht);

  // attention + Wo + velocity/residual (writes out0, out1)
  flash_attn<<<dim3(16, Hc, Bc), 256, 0, stream>>>(qhb, khb, vht, attn);
  transpose_cast<<<dim3(64, 64), tb, 0, stream>>>(wo, W, 2048, 2048, 0, 2048);
  gemm256<1, 2><<<256, 512, 0, stream>>>(attn, 2048, W, out0, nullptr, x, vel, lb, out1,
                                         2048, 2048, 16);

  // FFN
  rmsnorm_cast<<<Rc, 256, 0, stream>>>(out0, ffnw, normed);
  transpose_cast<<<dim3(176, 64), tb, 0, stream>>>(w1, W, 2048, 5632, 0, 2048);
  gemm256<2, 2><<<704, 512, 0, stream>>>(normed, 2048, W, nullptr, gbuf, nullptr, nullptr,
                                         nullptr, nullptr, 2048, 11264, 44);
  transpose_cast<<<dim3(176, 64), tb, 0, stream>>>(w3, W, 2048, 5632, 0, 2048);
  gemm256<2, 2><<<704, 512, 0, stream>>>(normed, 2048, W, nullptr, gbuf + FFNc, nullptr,
                                         nullptr, nullptr, nullptr, 2048, 11264, 44);
  silu_mul_ip<<<dim3(11, 1024), 256, 0, stream>>>(gbuf);
  transpose_cast<<<dim3(64, 176), tb, 0, stream>>>(w2, W, 5632, 2048, 0, 5632);
  gemm256<3, 2><<<256, 512, 0, stream>>>(gbuf, 11264, W, out0, nullptr, out0, nullptr,
                                         nullptr, nullptr, 5632, 2048, 16);
}

// Round 3
// 935.998 us; speedup vs baseline: 1.1236x; 1.1236x over previous
//
#include <hip/hip_runtime.h>
#include <cstdint>
#include <cstddef>

typedef __bf16 bf16;
typedef __bf16 bf16x2 __attribute__((ext_vector_type(2)));
typedef __bf16 bf16x8 __attribute__((ext_vector_type(8)));
typedef float  f32x4  __attribute__((ext_vector_type(4)));

#define DEV __device__ __forceinline__

constexpr int Bc = 2, Sc = 2048, Dc = 2048, Hc = 16, KVc = 4, HDc = 128, FFNc = 5632;
constexpr int Rc = Bc * Sc;  // 4096 rows

DEV void async16(const bf16* g, bf16* l) {
  __builtin_amdgcn_global_load_lds((const __attribute__((address_space(1))) void*)g,
                                   (__attribute__((address_space(3))) void*)l, 16, 0, 0);
}

// ---------------- weight transpose + fp32->bf16 cast: out[n][k] = in[k][n] ----
__global__ void transpose_cast(const float* __restrict__ in, bf16* __restrict__ out,
                               int K, int N, int rowoff, int ldout) {
  __shared__ float tile[32][33];
  int k0 = blockIdx.y * 32, n0 = blockIdx.x * 32;
  int tx = threadIdx.x, ty = threadIdx.y;
  for (int r = ty; r < 32; r += 8)
    tile[r][tx] = in[(size_t)(k0 + r) * N + n0 + tx];
  __syncthreads();
  for (int r = ty; r < 32; r += 8)
    out[(size_t)(rowoff + n0 + r) * ldout + k0 + tx] = (bf16)tile[tx][r];
}

// ---------------- V transpose: vht[b][g][d][s] = qkvb[b*S+s][2560+g*128+d] ---
__global__ void transpose_v(const bf16* __restrict__ qkvb, bf16* __restrict__ vht) {
  __shared__ bf16 tile[32][33];
  int s0 = blockIdx.x * 32, d0 = blockIdx.y * 32, bg = blockIdx.z;  // bg = b*4+g
  int tx = threadIdx.x, ty = threadIdx.y;
  int b = bg >> 2, g = bg & 3;
  const bf16* src = qkvb + (size_t)(b * Sc) * 3072 + 2560 + g * 128;
  for (int r = ty; r < 32; r += 8)
    tile[r][tx] = src[(size_t)(s0 + r) * 3072 + d0 + tx];
  __syncthreads();
  bf16* dst = vht + ((size_t)bg * HDc) * Sc;
  for (int r = ty; r < 32; r += 8)
    dst[(size_t)(d0 + r) * Sc + s0 + tx] = tile[tx][r];
}

// ---------------- row RMSNorm (D=2048) + cast to bf16 ------------------------
__global__ void rmsnorm_cast(const float* __restrict__ x, const float* __restrict__ w,
                             bf16* __restrict__ out) {
  __shared__ float red[4];
  int row = blockIdx.x, tid = threadIdx.x;
  const float* xr = x + (size_t)row * Dc;
  float ss = 0.f;
#pragma unroll
  for (int i = 0; i < Dc / 256; ++i) { float v = xr[tid + i * 256]; ss += v * v; }
  for (int off = 32; off; off >>= 1) ss += __shfl_xor(ss, off);
  if ((tid & 63) == 0) red[tid >> 6] = ss;
  __syncthreads();
  float rstd = rsqrtf((red[0] + red[1] + red[2] + red[3]) * (1.f / Dc) + 1e-6f);
  bf16* orow = out + (size_t)row * Dc;
#pragma unroll
  for (int i = 0; i < Dc / 256; ++i) {
    int j = tid + i * 256;
    orow[j] = (bf16)(xr[j] * rstd * w[j]);
  }
}

// ---------------- 256x128 deep-pipelined GEMM (T2+T3+T4+T5, ring-3) ----------
// C[M,N] = A[M,K] * Bt[N,K]^T ; K % 64 == 0, M % 256 == 0, N % 128 == 0.
// 8 waves (2m x 4n), per-wave 128x32 output (8 m-frags x 2 n-frags).
// BK=64, ring-3 LDS (144KB), counted vmcnt(6) (never 0 mid-loop),
// 2 sub-phases/tile of 16 MFMA each, 3 barriers/tile, swizzled conflict-free LDS.
// MODE 1: v=clip(beta*velin+c); velout=v; Cf = xin + v
// MODE 2: store bf16 C at ldc
// MODE 3: Cf = xin + c (in-place residual ok)
template <int MODE>
__global__ __launch_bounds__(512, 2) void gemm128(
    const bf16* __restrict__ A, int lda, const bf16* __restrict__ Bt,
    float* __restrict__ Cf, bf16* __restrict__ Cb,
    const float* __restrict__ xin, const float* __restrict__ velin,
    const float* __restrict__ lbp, float* __restrict__ velout,
    int K, int ldc, int nbx) {
  __shared__ bf16 Asb[3][2 * 8192];  // 3 rings x (256 rows x 64 k) = 96KB
  __shared__ bf16 Bsb[3][8192];      // 3 rings x (128 rows x 64 k) = 48KB
  const int tid = threadIdx.x, lane = tid & 63, w = tid >> 6;
  const int quad = lane >> 4, l15 = lane & 15;
  const int wm = w >> 2, wn = w & 3;

  // bijective XCD-chunked swizzle (m204)
  const int nwg = gridDim.x, bid = blockIdx.x;
  const int qq = nwg >> 3, rr = nwg & 7, xcd = bid & 7, lid = bid >> 3;
  const int swz = (xcd < rr ? xcd * (qq + 1) : rr * (qq + 1) + (xcd - rr) * qq) + lid;
  const int m0 = (swz / nbx) * 256, n0 = (swz % nbx) * 128;

  const int NT = K >> 6;

  f32x4 acc[8][2];
  const f32x4 zf = {0.f, 0.f, 0.f, 0.f};
#pragma unroll
  for (int i = 0; i < 8; ++i) { acc[i][0] = zf; acc[i][1] = zf; }

  // staging source pointers: linear LDS dest + inverse-swizzled global source.
  // thread covers LDS row (tid>>3) (+64/+128 offsets), 16B slot (tid&7);
  // slot s of row r holds global k-chunk (s ^ (r&7)).
  const int srow = tid >> 3, schk = tid & 7;
  const bf16* srcA[2][2];
  const bf16* srcB[2];
#pragma unroll
  for (int h = 0; h < 2; ++h)
#pragma unroll
    for (int j = 0; j < 2; ++j) {
      int row = h * 128 + j * 64 + srow;
      srcA[h][j] = A + (size_t)(m0 + row) * lda + ((schk ^ (row & 7)) * 8);
    }
#pragma unroll
  for (int j = 0; j < 2; ++j) {
    int row = j * 64 + srow;
    srcB[j] = Bt + (size_t)(n0 + row) * K + ((schk ^ (row & 7)) * 8);
  }

  auto stage = [&](int t, int ring) {  // 6 async16 per thread
    const int koff = t * 64;
    bf16* Al = Asb[ring];
    bf16* Bl = Bsb[ring];
#pragma unroll
    for (int h = 0; h < 2; ++h)
#pragma unroll
      for (int j = 0; j < 2; ++j)
        async16(srcA[h][j] + koff, Al + h * 8192 + j * 4096 + w * 512);
#pragma unroll
    for (int j = 0; j < 2; ++j)
      async16(srcB[j] + koff, Bl + j * 4096 + w * 512);
  };

  // swizzled k-chunk offsets for ds_read (row&7 == l15&7 for all our rows)
  const int ac0 = ((quad) ^ (l15 & 7)) * 8;
  const int ac1 = ((4 + quad) ^ (l15 & 7)) * 8;

  // prologue: two tiles in flight
  stage(0, 0);
  stage(1, 1);

  int r0 = 0;
  for (int t = 0; t < NT; ++t) {
    if (t == NT - 1) asm volatile("s_waitcnt vmcnt(0)" ::: "memory");
    else             asm volatile("s_waitcnt vmcnt(6)" ::: "memory");  // tile t landed; t+1 in flight
    __builtin_amdgcn_s_barrier();  // [A] all waves' tile-t data visible

    const bf16* Ab = Asb[r0] + wm * 8192;
    const bf16* Bb = Bsb[r0];

    // ---- sub-phase 0: A m-frags 0..3 + both B frags ----
    bf16x8 af[4][2], bfr[2][2];
#pragma unroll
    for (int i = 0; i < 4; ++i) {
      af[i][0] = *(const bf16x8*)(Ab + (i * 16 + l15) * 64 + ac0);
      af[i][1] = *(const bf16x8*)(Ab + (i * 16 + l15) * 64 + ac1);
    }
#pragma unroll
    for (int nf = 0; nf < 2; ++nf) {
      bfr[nf][0] = *(const bf16x8*)(Bb + (wn * 32 + nf * 16 + l15) * 64 + ac0);
      bfr[nf][1] = *(const bf16x8*)(Bb + (wn * 32 + nf * 16 + l15) * 64 + ac1);
    }
    {
      int r2 = r0 + 2; if (r2 >= 3) r2 -= 3;
      if (t + 2 < NT) stage(t + 2, r2);  // region r2 dead since tile t-1 completed
    }
    __builtin_amdgcn_sched_barrier(0);
    __builtin_amdgcn_s_barrier();  // [B]
    __builtin_amdgcn_s_setprio(1);
#pragma unroll
    for (int kh = 0; kh < 2; ++kh)
#pragma unroll
      for (int i = 0; i < 4; ++i)
#pragma unroll
        for (int nf = 0; nf < 2; ++nf)
          acc[i][nf] = __builtin_amdgcn_mfma_f32_16x16x32_bf16(af[i][kh], bfr[nf][kh], acc[i][nf], 0, 0, 0);
    __builtin_amdgcn_s_setprio(0);

    // ---- sub-phase 1: A m-frags 4..7 (B frags still live) ----
#pragma unroll
    for (int i = 0; i < 4; ++i) {
      af[i][0] = *(const bf16x8*)(Ab + ((i + 4) * 16 + l15) * 64 + ac0);
      af[i][1] = *(const bf16x8*)(Ab + ((i + 4) * 16 + l15) * 64 + ac1);
    }
    __builtin_amdgcn_sched_barrier(0);
    __builtin_amdgcn_s_barrier();  // [D]
    __builtin_amdgcn_s_setprio(1);
#pragma unroll
    for (int kh = 0; kh < 2; ++kh)
#pragma unroll
      for (int i = 0; i < 4; ++i)
#pragma unroll
        for (int nf = 0; nf < 2; ++nf)
          acc[4 + i][nf] = __builtin_amdgcn_mfma_f32_16x16x32_bf16(af[i][kh], bfr[nf][kh], acc[4 + i][nf], 0, 0, 0);
    __builtin_amdgcn_s_setprio(0);

    r0 = (r0 == 2) ? 0 : r0 + 1;
  }

  float beta = 0.f;
  if (MODE == 1) beta = 1.f / (1.f + __expf(-lbp[0]));
#pragma unroll
  for (int i = 0; i < 8; ++i) {
#pragma unroll
    for (int nf = 0; nf < 2; ++nf) {
#pragma unroll
      for (int r = 0; r < 4; ++r) {
        int row = m0 + wm * 128 + i * 16 + quad * 4 + r;
        int col = n0 + wn * 32 + nf * 16 + l15;
        size_t idx = (size_t)row * ldc + col;
        float c = acc[i][nf][r];
        if (MODE == 1) {
          float v = beta * velin[idx] + c;
          v = fminf(8.f, fmaxf(-8.f, v));
          velout[idx] = v;
          Cf[idx] = xin[idx] + v;
        } else if (MODE == 2) {
          Cb[idx] = (bf16)c;
        } else {
          Cf[idx] = xin[idx] + c;
        }
      }
    }
  }
}

// ---------------- per-head RMSNorm + RoPE for q,k (v handled separately) -----
// q outputs pre-scaled by 1/sqrt(HD).
__global__ __launch_bounds__(256) void qk_norm_rope(
    const bf16* __restrict__ qkv, const float* __restrict__ qw, const float* __restrict__ kw,
    const float* __restrict__ freqs, bf16* __restrict__ qh, bf16* __restrict__ kh) {
  int row = blockIdx.x;  // b*S + s
  int b = row >> 11, s = row & 2047;
  int tid = threadIdx.x, wvid = tid >> 6, lane = tid & 63;
  float cs = freqs[(size_t)(s * 64 + lane) * 2 + 0];
  float sn = freqs[(size_t)(s * 64 + lane) * 2 + 1];
  for (int slot = wvid; slot < 20; slot += 4) {
    const bf16* base = qkv + (size_t)row * 3072 + slot * 128;
    float t0 = (float)base[2 * lane], t1 = (float)base[2 * lane + 1];
    float ss = t0 * t0 + t1 * t1;
    for (int off = 32; off; off >>= 1) ss += __shfl_xor(ss, off);
    float rstd = rsqrtf(ss * (1.f / 128.f) + 1e-6f);
    const float* w = (slot < 16) ? qw : kw;
    float sc = (slot < 16) ? 0.08838834764831845f : 1.f;  // fold 1/sqrt(128) into q
    float n0 = t0 * rstd * w[2 * lane], n1 = t1 * rstd * w[2 * lane + 1];
    bf16x2 o;
    o[0] = (bf16)((n0 * cs - n1 * sn) * sc);
    o[1] = (bf16)((n0 * sn + n1 * cs) * sc);
    if (slot < 16)
      *(bf16x2*)(qh + ((size_t)(b * Hc + slot) * Sc + s) * HDc + 2 * lane) = o;
    else
      *(bf16x2*)(kh + ((size_t)(b * KVc + (slot - 16)) * Sc + s) * HDc + 2 * lane) = o;
  }
}

// ---------------- strict-causal GQA flash attention (v2) ---------------------
__global__ __launch_bounds__(256) void flash_attn(
    const bf16* __restrict__ qh, const bf16* __restrict__ kh, const bf16* __restrict__ vht,
    bf16* __restrict__ attn) {
  __shared__ bf16 Ks[2][64 * 128];   // [k][d] linear, content XOR-swizzled by (row&15)<<4
  __shared__ bf16 Vs[2][128 * 64];   // [d][k] linear, content XOR-swizzled by (row&7)<<4
  __shared__ bf16 Ps[4][16 * 68];    // per-wave P transpose scratch, pitch 68 (2-way free)
  const int tid = threadIdx.x, lane = tid & 63, wvid = tid >> 6;
  const int quad = lane >> 4, l15 = lane & 15;
  const int pairp = blockIdx.x;
  const int h = blockIdx.y, b = blockIdx.z, g = h >> 2;
  const bf16* qbase = qh + (size_t)(b * Hc + h) * Sc * HDc;
  const bf16* kbase = kh + (size_t)(b * KVc + g) * Sc * HDc;
  const bf16* vbase = vht + (size_t)(b * KVc + g) * HDc * Sc;  // [d][s]
  const f32x4 zf = {0.f, 0.f, 0.f, 0.f};
  bf16* pw = Ps[wvid];

  bf16x8 ones;
#pragma unroll
  for (int e = 0; e < 8; ++e) ones[e] = (bf16)1.0f;

  int kcol[4], vcol[2];
#pragma unroll
  for (int f = 0; f < 4; ++f) kcol[f] = ((f * 64 + quad * 16) ^ (l15 << 4)) >> 1;
#pragma unroll
  for (int ks = 0; ks < 2; ++ks) vcol[ks] = ((ks * 64 + quad * 16) ^ ((l15 & 7) << 4)) >> 1;

  auto stage = [&](int kt2, int bsel) {
    const int k0s = kt2 * 64;
#pragma unroll
    for (int r = 0; r < 4; ++r) {
      int krow = (wvid * 4 + r) * 4 + quad;  // 0..63
      const bf16* src = kbase + (size_t)(k0s + krow) * HDc + ((l15 ^ (krow & 15)) * 8);
      async16(src, &Ks[bsel][(wvid * 4 + r) * 512]);
    }
#pragma unroll
    for (int r = 0; r < 4; ++r) {
      int vrow = (wvid * 4 + r) * 8 + (lane >> 3);  // 0..127
      int c8 = lane & 7;
      const bf16* src = vbase + (size_t)vrow * Sc + k0s + ((c8 ^ (vrow & 7)) * 8);
      async16(src, &Vs[bsel][(wvid * 4 + r) * 512]);
    }
  };

  for (int pass = 0; pass < 2; ++pass) {
    const int qt = pass ? 31 - pairp : pairp;
    const int q0 = qt * 64 + wvid * 16;

    bf16x8 qf[4];
#pragma unroll
    for (int f = 0; f < 4; ++f)
      qf[f] = *(const bf16x8*)(qbase + (size_t)(q0 + l15) * HDc + f * 32 + quad * 8);

    f32x4 Oa[8];
#pragma unroll
    for (int i = 0; i < 8; ++i) Oa[i] = zf;
    float m_i[4], l_i[4];
#pragma unroll
    for (int r = 0; r < 4; ++r) { m_i[r] = -3e38f; l_i[r] = 0.f; }

    const int ntiles = qt + 1;

    __syncthreads();
    stage(0, 0);

    for (int kt = 0; kt < ntiles; ++kt) {
      const int buf = kt & 1;
      const int k0 = kt * 64;
      __syncthreads();
      if (kt + 1 < ntiles) stage(kt + 1, buf ^ 1);

      f32x4 sc[4];
#pragma unroll
      for (int ks = 0; ks < 4; ++ks) {
        sc[ks] = zf;
#pragma unroll
        for (int f = 0; f < 4; ++f) {
          bf16x8 kf = *(const bf16x8*)(&Ks[buf][ks * 2048 + l15 * 128 + kcol[f]]);
          sc[ks] = __builtin_amdgcn_mfma_f32_16x16x32_bf16(qf[f], kf, sc[ks], 0, 0, 0);
        }
      }

      if (kt == qt) {
#pragma unroll
        for (int r = 0; r < 4; ++r) {
          int qg = q0 + quad * 4 + r;
#pragma unroll
          for (int ks = 0; ks < 4; ++ks)
            if (k0 + ks * 16 + l15 >= qg) sc[ks][r] = -3e38f;  // strict causal k<q
        }
      }

      float mx[4], al[4];
#pragma unroll
      for (int r = 0; r < 4; ++r)
        mx[r] = fmaxf(fmaxf(sc[0][r], sc[1][r]), fmaxf(sc[2][r], sc[3][r]));
#pragma unroll
      for (int off = 8; off; off >>= 1)
#pragma unroll
        for (int r = 0; r < 4; ++r) mx[r] = fmaxf(mx[r], __shfl_xor(mx[r], off));
#pragma unroll
      for (int r = 0; r < 4; ++r) {
        float mn = fmaxf(m_i[r], mx[r]);
        al[r] = __expf(m_i[r] - mn);
        m_i[r] = mn;
#pragma unroll
        for (int ks = 0; ks < 4; ++ks) {
          float p = (sc[ks][r] > -1e37f) ? __expf(sc[ks][r] - mn) : 0.f;
          sc[ks][r] = p;
        }
      }

#pragma unroll
      for (int r = 0; r < 4; ++r)
#pragma unroll
        for (int ks = 0; ks < 4; ++ks)
          pw[(quad * 4 + r) * 68 + ks * 16 + l15] = (bf16)sc[ks][r];

#pragma unroll
      for (int i = 0; i < 8; ++i)
#pragma unroll
        for (int r = 0; r < 4; ++r) Oa[i][r] *= al[r];

      bf16x8 pf0 = *(const bf16x8*)(pw + l15 * 68 + quad * 8);
      bf16x8 pf1 = *(const bf16x8*)(pw + l15 * 68 + 32 + quad * 8);

      f32x4 ls = zf;
      ls = __builtin_amdgcn_mfma_f32_16x16x32_bf16(pf0, ones, ls, 0, 0, 0);
      ls = __builtin_amdgcn_mfma_f32_16x16x32_bf16(pf1, ones, ls, 0, 0, 0);

#pragma unroll
      for (int i = 0; i < 8; ++i) {
        bf16x8 vf0 = *(const bf16x8*)(&Vs[buf][(i * 16 + l15) * 64 + vcol[0]]);
        Oa[i] = __builtin_amdgcn_mfma_f32_16x16x32_bf16(pf0, vf0, Oa[i], 0, 0, 0);
        bf16x8 vf1 = *(const bf16x8*)(&Vs[buf][(i * 16 + l15) * 64 + vcol[1]]);
        Oa[i] = __builtin_amdgcn_mfma_f32_16x16x32_bf16(pf1, vf1, Oa[i], 0, 0, 0);
      }
#pragma unroll
      for (int r = 0; r < 4; ++r) l_i[r] = l_i[r] * al[r] + ls[r];
    }

#pragma unroll
    for (int r = 0; r < 4; ++r) {
      float inv = (l_i[r] > 0.f) ? 1.f / l_i[r] : 0.f;
      int qg = q0 + quad * 4 + r;
      bf16* orow = attn + (size_t)(b * Sc + qg) * Dc + h * HDc;
#pragma unroll
      for (int i = 0; i < 8; ++i) orow[i * 16 + l15] = (bf16)(Oa[i][r] * inv);
    }
  }
}

// ---------------- SwiGLU in-place: g[:, :5632] = silu(g1)*g3 -----------------
__global__ __launch_bounds__(256) void silu_mul_ip(bf16* __restrict__ g) {
  int row = blockIdx.y * 4 + (threadIdx.x >> 6);
  int j0 = (blockIdx.x * 64 + (threadIdx.x & 63)) * 8;
  bf16* p = g + (size_t)row * (2 * FFNc) + j0;
  const bf16x8 a = *(const bf16x8*)p;
  const bf16x8 bb = *(const bf16x8*)(p + FFNc);
  bf16x8 o;
#pragma unroll
  for (int e = 0; e < 8; ++e) {
    float xa = (float)a[e], xb = (float)bb[e];
    float s = xa / (1.f + __expf(-xa));
    o[e] = (bf16)(s * xb);
  }
  *(bf16x8*)p = o;
}

// ---------------- launch ------------------------------------------------------
extern "C" void kernel_launch(void* const* d_in, const int* in_sizes, int n_in,
                              void* d_out, int out_size, void* d_ws, size_t ws_size,
                              hipStream_t stream) {
  (void)in_sizes; (void)n_in; (void)out_size; (void)ws_size;
  const float* x    = (const float*)d_in[0];
  const float* vel  = (const float*)d_in[1];
  const float* frq  = (const float*)d_in[2];
  const float* prew = (const float*)d_in[3];
  const float* wq   = (const float*)d_in[4];
  const float* wk   = (const float*)d_in[5];
  const float* wvw  = (const float*)d_in[6];
  const float* wo   = (const float*)d_in[7];
  const float* qnw  = (const float*)d_in[8];
  const float* knw  = (const float*)d_in[9];
  const float* lb   = (const float*)d_in[10];
  const float* ffnw = (const float*)d_in[11];
  const float* w1   = (const float*)d_in[12];
  const float* w3   = (const float*)d_in[13];
  const float* w2   = (const float*)d_in[14];

  float* out0 = (float*)d_out;                  // final x (also residual scratch)
  float* out1 = out0 + (size_t)Rc * Dc;         // velocity

  // ---- workspace arena ----
  char* ws = (char*)d_ws;
  bf16* W  = (bf16*)ws;                                   // 23.07 MB weight region (serial reuse)
  bf16* R1 = (bf16*)(ws + (size_t)23068672);              // 16.78 MB: hbuf -> attn -> normed
  bf16* G  = (bf16*)(ws + (size_t)23068672 + 16777216);   // 92.27 MB: qkv/heads -> gbuf
  bf16* hbuf   = R1;
  bf16* attn   = R1;
  bf16* normed = R1;
  bf16* qkvb   = G;                                       // 4096 x 3072 bf16
  bf16* qhb    = G + (size_t)4096 * 3072;                 // 2*16*2048*128
  bf16* khb    = qhb + (size_t)2 * 16 * 2048 * 128;       // 2*4*2048*128
  bf16* vht    = khb + (size_t)2 * 4 * 2048 * 128;        // V^T [b][g][128][2048]
  bf16* gbuf   = G;                                       // 4096 x 11264 (born after heads die)

  dim3 tb(32, 8);

  // QKV projection (M=4096, N=3072, K=2048): 16x24 = 384 blocks
  transpose_cast<<<dim3(64, 64), tb, 0, stream>>>(wq, W, 2048, 2048, 0, 2048);
  transpose_cast<<<dim3(16, 64), tb, 0, stream>>>(wk, W, 2048, 512, 2048, 2048);
  transpose_cast<<<dim3(16, 64), tb, 0, stream>>>(wvw, W, 2048, 512, 2560, 2048);
  rmsnorm_cast<<<Rc, 256, 0, stream>>>(x, prew, hbuf);
  gemm128<2><<<384, 512, 0, stream>>>(hbuf, 2048, W, nullptr, qkvb, nullptr, nullptr,
                                      nullptr, nullptr, 2048, 3072, 24);
  qk_norm_rope<<<Rc, 256, 0, stream>>>(qkvb, qnw, knw, frq, qhb, khb);
  transpose_v<<<dim3(64, 4, 8), tb, 0, stream>>>(qkvb, vht);

  // attention + Wo + velocity/residual (writes out0, out1): 16x16 = 256 blocks
  flash_attn<<<dim3(16, Hc, Bc), 256, 0, stream>>>(qhb, khb, vht, attn);
  transpose_cast<<<dim3(64, 64), tb, 0, stream>>>(wo, W, 2048, 2048, 0, 2048);
  gemm128<1><<<256, 512, 0, stream>>>(attn, 2048, W, out0, nullptr, x, vel, lb, out1,
                                      2048, 2048, 16);

  // FFN: 16x44 = 704 blocks each; down 16x16 = 256 blocks, K=5632
  rmsnorm_cast<<<Rc, 256, 0, stream>>>(out0, ffnw, normed);
  transpose_cast<<<dim3(176, 64), tb, 0, stream>>>(w1, W, 2048, 5632, 0, 2048);
  gemm128<2><<<704, 512, 0, stream>>>(normed, 2048, W, nullptr, gbuf, nullptr, nullptr,
                                      nullptr, nullptr, 2048, 11264, 44);
  transpose_cast<<<dim3(176, 64), tb, 0, stream>>>(w3, W, 2048, 5632, 0, 2048);
  gemm128<2><<<704, 512, 0, stream>>>(normed, 2048, W, nullptr, gbuf + FFNc, nullptr,
                                      nullptr, nullptr, nullptr, 2048, 11264, 44);
  silu_mul_ip<<<dim3(11, 1024), 256, 0, stream>>>(gbuf);
  transpose_cast<<<dim3(64, 176), tb, 0, stream>>>(w2, W, 5632, 2048, 0, 5632);
  gemm128<3><<<256, 512, 0, stream>>>(gbuf, 11264, W, out0, nullptr, out0, nullptr,
                                      nullptr, nullptr, 5632, 2048, 16);
}